// Round 1
// 634.381 us; speedup vs baseline: 1.0737x; 1.0737x over previous
//
#include <hip/hip_runtime.h>

// Self-attention (channel-attention variant), B=8 N=4096 C=1024 H=16 D=64.
// FP16 pipeline. cvt(x)->f16; cvt(W*) one dispatch; single QKV GEMM (N=3072,
// Q/K transposed [ch][token], V natural); attention: partial logits -> softmax
// -> PV; final GEMM y@Wp^T + bp -> fp32 d_out.
//
// GEMM core (this round): 256x256 tile, 8 waves (2Mx4N, 128x64/wave), BK=64,
// double-buffered 128KiB LDS, 4-phase/K-tile schedule with counted vmcnt
// (never drains to 0 in steady state), XOR-swizzled LDS (linear global_load_lds
// dest + pre-swizzled global source + swizzled ds_read_b128), s_setprio around
// MFMA clusters, bijective XCD blockIdx swizzle.

typedef __attribute__((ext_vector_type(4))) float f32x4;
typedef __attribute__((ext_vector_type(8))) _Float16 f16x8;
typedef __attribute__((ext_vector_type(4))) unsigned short u16x4;
typedef __attribute__((ext_vector_type(8))) unsigned short u16x8;

__device__ __forceinline__ unsigned short f2h(float f) {
  union { _Float16 h; unsigned short u; } v;
  v.h = (_Float16)f;  // RNE
  return v.u;
}

__global__ void cvt_f32_f16(const float* __restrict__ in, unsigned short* __restrict__ out, int n) {
  int i = (blockIdx.x * blockDim.x + threadIdx.x) * 4;
  if (i >= n) return;
  float4 v = *(const float4*)(in + i);
  u16x4 o;
  o.x = f2h(v.x); o.y = f2h(v.y); o.z = f2h(v.z); o.w = f2h(v.w);
  *(u16x4*)(out + i) = o;
}

// 4 weight matrices (1M elems each) in one dispatch; blockIdx.y selects.
__global__ void cvt4_f32_f16(const float* __restrict__ s0, const float* __restrict__ s1,
                             const float* __restrict__ s2, const float* __restrict__ s3,
                             unsigned short* __restrict__ d0, unsigned short* __restrict__ d1,
                             unsigned short* __restrict__ d2, unsigned short* __restrict__ d3) {
  const float* src; unsigned short* dst;
  switch (blockIdx.y) {
    case 0: src = s0; dst = d0; break;
    case 1: src = s1; dst = d1; break;
    case 2: src = s2; dst = d2; break;
    default: src = s3; dst = d3; break;
  }
  int i = (blockIdx.x * blockDim.x + threadIdx.x) * 4;
  float4 v = *(const float4*)(src + i);
  u16x4 o;
  o.x = f2h(v.x); o.y = f2h(v.y); o.z = f2h(v.z); o.w = f2h(v.w);
  *(u16x4*)(dst + i) = o;
}

// ---------------- GEMM: C = A(MxK) * Bt(NxK)^T, fp16 in, 256x256 tile ----------------
enum { EPI_QKV = 0, EPI_F32_BIAS = 2 };

#define GLD(SRC, DST)                                                                   \
  __builtin_amdgcn_global_load_lds((const __attribute__((address_space(1))) void*)(SRC), \
                                   (__attribute__((address_space(3))) void*)(DST), 16, 0, 0)
// asm barrier doubles as compiler memory fence (raw builtin barrier is not a fence;
// cross-wave stage->read ordering needs reads pinned below the barrier).
#define SBAR() asm volatile("s_barrier" ::: "memory")

template <int EPI>
__global__ __launch_bounds__(512, 2) void gemm256(const unsigned short* __restrict__ A,
                                                  const unsigned short* __restrict__ Bt,
                                                  void* __restrict__ Cv,
                                                  const float* __restrict__ bias,
                                                  const int M, const int N, const int K) {
  // staging: 2 buf x (A 16384 + B 16384) u16 = 131072 B. Epilogue repack (QKV only):
  // 8 waves x 9216 u16 = 147456 B (reuses staging region after final barrier).
  __shared__ unsigned short lds[EPI == EPI_QKV ? 73728 : 65536];
  const int tid = threadIdx.x;
  const int w = tid >> 6, lane = tid & 63;
  const int quad = lane >> 4, l15 = lane & 15;
  const int wm = w >> 2, wn = w & 3;  // wave grid 2(M) x 4(N); per-wave 128x64 output

  // bijective XCD swizzle (gridDim.x % 8 == 0): consecutive work per XCD -> B panel L2-hot
  const int cpx = (int)gridDim.x >> 3;
  const int wg = ((int)blockIdx.x & 7) * cpx + ((int)blockIdx.x >> 3);
  const int mt = M >> 8;
  const int bm = wg % mt, bn = wg / mt;
  const int m0 = bm << 8, n0 = bn << 8;

  // LDS content definition: LDS(row r, 16B-slot u) = global(row r, slot u ^ (r&7)).
  // global_load_lds writes linearly (base + lane*16B); lane l of a 1KB chunk starting
  // at row rb covers (rb + (l>>3), slot l&7) -> source slot (l&7)^(l>>3).
  const int srow = lane >> 3;
  const unsigned short* aSrc = A + (size_t)(m0 + srow) * K + (((lane & 7) ^ srow) << 3);
  const unsigned short* bSrc = Bt + (size_t)(n0 + srow) * K + (((lane & 7) ^ srow) << 3);

  // per-wave stage chunk row bases (each wave: 2x1KB chunks per 16KB group)
  const int rbA = (w >> 2) * 128 + (w & 3) * 16;  // A-mh0: rbA,rbA+8 ; A-mh1: +64
  const int rbB = (w >> 1) * 64 + (w & 1) * 16;   // B-nh0: rbB,rbB+8 ; B-nh1: +32

  // fragment read offsets (u16 units). row stride 64 u16 = 128B; k-slot XOR row&7
  // spreads the 16 l15-lanes over 8 slots -> 2 lanes/16B-slot on ds_read_b128 (free).
  const int arow = (wm * 128 + l15) << 6;
  const int brow = (wn * 64 + l15) << 6;
  const int ak0 = (quad ^ (l15 & 7)) << 3;
  const int ak1 = ((4 + quad) ^ (l15 & 7)) << 3;

  f32x4 acc[8][4];
#pragma unroll
  for (int i = 0; i < 8; ++i)
#pragma unroll
    for (int j = 0; j < 4; ++j) acc[i][j] = f32x4{0.f, 0.f, 0.f, 0.f};
  f16x8 af[4][2], bf[2][2][2];

  const int NT = K >> 6;

  // ---- prologue: stage tile 0 into buf0 (order: A-mh0, B-nh0, B-nh1, A-mh1) ----
  GLD(aSrc + (size_t)rbA * K, &lds[rbA * 64]);
  GLD(aSrc + (size_t)(rbA + 8) * K, &lds[(rbA + 8) * 64]);
  GLD(bSrc + (size_t)rbB * K, &lds[16384 + rbB * 64]);
  GLD(bSrc + (size_t)(rbB + 8) * K, &lds[16384 + (rbB + 8) * 64]);
  GLD(bSrc + (size_t)(rbB + 32) * K, &lds[16384 + (rbB + 32) * 64]);
  GLD(bSrc + (size_t)(rbB + 40) * K, &lds[16384 + (rbB + 40) * 64]);
  GLD(aSrc + (size_t)(rbA + 64) * K, &lds[(rbA + 64) * 64]);
  GLD(aSrc + (size_t)(rbA + 72) * K, &lds[(rbA + 72) * 64]);
  asm volatile("s_waitcnt vmcnt(4)" ::: "memory");  // A-mh0(0), B-nh0(0) landed
  SBAR();

  // Main loop. Phases per tile t (reads buf[t&1]; stages tile t+1 into other buf):
  //  ph1 (mh0,nh0): read A-mh0+B-nh0, stage A-mh0(t+1), MFMA, vmcnt(4) [->B-nh1(t) done]
  //  ph2 (mh0,nh1): read B-nh1,       stage B-nh0(t+1), MFMA, vmcnt(4) [->A-mh1(t) done]
  //  ph3 (mh1,nh0): read A-mh1,       stage B-nh1(t+1), MFMA
  //  ph4 (mh1,nh1): (regs only),      stage A-mh1(t+1), MFMA, vmcnt(4) [->t+1 ph1 ready]
  for (int t = 0; t < NT; ++t) {
    const int db = (t & 1) << 15;
    const int sb = ((t + 1) & 1) << 15;
    const int ks = (t + 1) << 6;
    const bool st = (t + 1) < NT;
    const bool last = (t + 1) == NT;

    // ---- phase 1 (mh=0, nh=0) ----
#pragma unroll
    for (int mi = 0; mi < 4; ++mi) {
      af[mi][0] = *(const f16x8*)&lds[db + arow + mi * 1024 + ak0];
      af[mi][1] = *(const f16x8*)&lds[db + arow + mi * 1024 + ak1];
    }
#pragma unroll
    for (int nn = 0; nn < 2; ++nn) {
      bf[0][nn][0] = *(const f16x8*)&lds[db + 16384 + brow + nn * 1024 + ak0];
      bf[0][nn][1] = *(const f16x8*)&lds[db + 16384 + brow + nn * 1024 + ak1];
    }
    if (st) {
      GLD(aSrc + (size_t)rbA * K + ks, &lds[sb + rbA * 64]);
      GLD(aSrc + (size_t)(rbA + 8) * K + ks, &lds[sb + (rbA + 8) * 64]);
    }
    SBAR();
    __builtin_amdgcn_s_setprio(1);
#pragma unroll
    for (int s = 0; s < 2; ++s)
#pragma unroll
      for (int mi = 0; mi < 4; ++mi)
#pragma unroll
        for (int nn = 0; nn < 2; ++nn)
          acc[mi][nn] = __builtin_amdgcn_mfma_f32_16x16x32_f16(af[mi][s], bf[0][nn][s], acc[mi][nn], 0, 0, 0);
    __builtin_amdgcn_s_setprio(0);
    if (!last) asm volatile("s_waitcnt vmcnt(4)" ::: "memory");
    else       asm volatile("s_waitcnt vmcnt(2)" ::: "memory");
    SBAR();

    // ---- phase 2 (mh=0, nh=1) ----
#pragma unroll
    for (int nn = 0; nn < 2; ++nn) {
      bf[1][nn][0] = *(const f16x8*)&lds[db + 16384 + brow + 2048 + nn * 1024 + ak0];
      bf[1][nn][1] = *(const f16x8*)&lds[db + 16384 + brow + 2048 + nn * 1024 + ak1];
    }
    if (st) {
      GLD(bSrc + (size_t)rbB * K + ks, &lds[sb + 16384 + rbB * 64]);
      GLD(bSrc + (size_t)(rbB + 8) * K + ks, &lds[sb + 16384 + (rbB + 8) * 64]);
    }
    SBAR();
    __builtin_amdgcn_s_setprio(1);
#pragma unroll
    for (int s = 0; s < 2; ++s)
#pragma unroll
      for (int mi = 0; mi < 4; ++mi)
#pragma unroll
        for (int nn = 0; nn < 2; ++nn)
          acc[mi][2 + nn] = __builtin_amdgcn_mfma_f32_16x16x32_f16(af[mi][s], bf[1][nn][s], acc[mi][2 + nn], 0, 0, 0);
    __builtin_amdgcn_s_setprio(0);
    if (!last) asm volatile("s_waitcnt vmcnt(4)" ::: "memory");
    else       asm volatile("s_waitcnt vmcnt(0)" ::: "memory");
    SBAR();

    // ---- phase 3 (mh=1, nh=0) ----
#pragma unroll
    for (int mi = 0; mi < 4; ++mi) {
      af[mi][0] = *(const f16x8*)&lds[db + arow + 4096 + mi * 1024 + ak0];
      af[mi][1] = *(const f16x8*)&lds[db + arow + 4096 + mi * 1024 + ak1];
    }
    if (st) {
      GLD(bSrc + (size_t)(rbB + 32) * K + ks, &lds[sb + 16384 + (rbB + 32) * 64]);
      GLD(bSrc + (size_t)(rbB + 40) * K + ks, &lds[sb + 16384 + (rbB + 40) * 64]);
    }
    SBAR();
    __builtin_amdgcn_s_setprio(1);
#pragma unroll
    for (int s = 0; s < 2; ++s)
#pragma unroll
      for (int mi = 0; mi < 4; ++mi)
#pragma unroll
        for (int nn = 0; nn < 2; ++nn)
          acc[4 + mi][nn] = __builtin_amdgcn_mfma_f32_16x16x32_f16(af[mi][s], bf[0][nn][s], acc[4 + mi][nn], 0, 0, 0);
    __builtin_amdgcn_s_setprio(0);
    SBAR();

    // ---- phase 4 (mh=1, nh=1): all operands already in regs ----
    if (st) {
      GLD(aSrc + (size_t)(rbA + 64) * K + ks, &lds[sb + (rbA + 64) * 64]);
      GLD(aSrc + (size_t)(rbA + 72) * K + ks, &lds[sb + (rbA + 72) * 64]);
    }
    SBAR();
    __builtin_amdgcn_s_setprio(1);
#pragma unroll
    for (int s = 0; s < 2; ++s)
#pragma unroll
      for (int mi = 0; mi < 4; ++mi)
#pragma unroll
        for (int nn = 0; nn < 2; ++nn)
          acc[4 + mi][2 + nn] = __builtin_amdgcn_mfma_f32_16x16x32_f16(af[mi][s], bf[1][nn][s], acc[4 + mi][2 + nn], 0, 0, 0);
    __builtin_amdgcn_s_setprio(0);
    if (st) asm volatile("s_waitcnt vmcnt(4)" ::: "memory");
    SBAR();
  }
  // After the final SBAR all waves' LDS reads are complete; staging region reusable.

  if (EPI == EPI_F32_BIAS) {
    float* C = (float*)Cv;
#pragma unroll
    for (int ni = 0; ni < 4; ++ni) {
      const int col = n0 + wn * 64 + ni * 16 + l15;
      const float bv = bias[col];
#pragma unroll
      for (int mi = 0; mi < 8; ++mi)
#pragma unroll
        for (int rr = 0; rr < 4; ++rr) {
          const int row = m0 + wm * 128 + mi * 16 + quad * 4 + rr;
          C[(size_t)row * N + col] = acc[mi][ni][rr] + bv;
        }
    }
  } else {
    // EPI_QKV: n0 < 2048 -> Q/K channels, transposed [channel][token];
    //          n0 >= 2048 -> V, natural [token][channel] at Cv + 2048*M elems.
    unsigned short* C = (unsigned short*)Cv;
    const bool isT = (n0 < 2048);
    unsigned short* wreg = &lds[w * 9216];  // per-wave repack region
    if (isT) {
      // [ch 64][tok 128], stride 136 (16B-aligned rows)
#pragma unroll
      for (int mi = 0; mi < 8; ++mi)
#pragma unroll
        for (int ni = 0; ni < 4; ++ni)
#pragma unroll
          for (int rr = 0; rr < 4; ++rr)
            wreg[(ni * 16 + l15) * 136 + mi * 16 + quad * 4 + rr] = f2h(acc[mi][ni][rr]);
#pragma unroll
      for (int p = 0; p < 16; ++p) {
        const int ch = p * 4 + quad;
        u16x8 v = *(const u16x8*)&wreg[ch * 136 + l15 * 8];
        *(u16x8*)&C[(size_t)(n0 + wn * 64 + ch) * M + m0 + wm * 128 + l15 * 8] = v;
      }
    } else {
      // [tok 128][ch 64], stride 72
#pragma unroll
      for (int mi = 0; mi < 8; ++mi)
#pragma unroll
        for (int ni = 0; ni < 4; ++ni)
#pragma unroll
          for (int rr = 0; rr < 4; ++rr)
            wreg[(mi * 16 + quad * 4 + rr) * 72 + ni * 16 + l15] = f2h(acc[mi][ni][rr]);
#pragma unroll
      for (int p = 0; p < 16; ++p) {
        const int tok = p * 8 + (lane >> 3);
        u16x8 v = *(const u16x8*)&wreg[tok * 72 + (lane & 7) * 8];
        *(u16x8*)&C[(size_t)2048 * M + (size_t)(m0 + wm * 128 + tok) * 1024 +
                    (n0 - 2048) + wn * 64 + (lane & 7) * 8] = v;
      }
    }
  }
}

// ---------------- attention stage 1: partial logits over 256-token chunks ----------------
// qkt: [2048][32768] f16 (rows 0..1023 Q channels, 1024..2047 K channels)
// pbuf: [128][16][64][64] f32 raw partial sums (no scale)
__global__ __launch_bounds__(256) void attn_logits(const unsigned short* __restrict__ qkt,
                                                   float* __restrict__ pbuf) {
  const int h = blockIdx.x, b = blockIdx.y, s = blockIdx.z;
  const int tid = threadIdx.x;
  const int wave = tid >> 6, lane = tid & 63;
  const int quad = lane >> 4, l15 = lane & 15;

  f32x4 acc[4];
#pragma unroll
  for (int t = 0; t < 4; t++) acc[t] = f32x4{0.f, 0.f, 0.f, 0.f};

  const unsigned short* qp =
      qkt + (size_t)(h * 64 + wave * 16 + l15) * 32768 + b * 4096 + s * 256 + quad * 8;
  const unsigned short* kp[4];
#pragma unroll
  for (int et = 0; et < 4; et++)
    kp[et] = qkt + (size_t)(1024 + h * 64 + et * 16 + l15) * 32768 + b * 4096 + s * 256 + quad * 8;

#pragma unroll 2
  for (int k0 = 0; k0 < 256; k0 += 32) {
    f16x8 aq = *(const f16x8*)(qp + k0);
#pragma unroll
    for (int et = 0; et < 4; et++) {
      f16x8 bk = *(const f16x8*)(kp[et] + k0);
      acc[et] = __builtin_amdgcn_mfma_f32_16x16x32_f16(aq, bk, acc[et], 0, 0, 0);
    }
  }

  float* pb = pbuf + ((size_t)(b * 16 + h) * 16 + s) * 4096;
#pragma unroll
  for (int et = 0; et < 4; et++)
#pragma unroll
    for (int rr = 0; rr < 4; rr++)
      pb[(wave * 16 + quad * 4 + rr) * 64 + et * 16 + l15] = acc[et][rr];
}

// ---------------- attention stage 2: reduce partials + softmax -> P f16 ----------------
// grid 512 = (bh, d-group of 16); thread t: d = dg*16 + (t>>4), e = (t&15)*4 .. +4
__global__ __launch_bounds__(256) void attn_softmax(const float* __restrict__ pbuf,
                                                    unsigned short* __restrict__ pP) {
  const int bh = blockIdx.x >> 2, dg = blockIdx.x & 3;
  const int t = threadIdx.x;
  const int d = dg * 16 + (t >> 4), e4 = t & 15;
  const float* pb = pbuf + (size_t)bh * 65536 + d * 64 + e4 * 4;

  float v[4] = {0.f, 0.f, 0.f, 0.f};
  for (int s = 0; s < 16; s++) {
    float4 tt = *(const float4*)(pb + s * 4096);
    v[0] += tt.x; v[1] += tt.y; v[2] += tt.z; v[3] += tt.w;
  }
#pragma unroll
  for (int i = 0; i < 4; i++) v[i] *= 0.125f;  // SCALE = D^-0.5

  float m = fmaxf(fmaxf(v[0], v[1]), fmaxf(v[2], v[3]));
#pragma unroll
  for (int o = 1; o < 16; o <<= 1) m = fmaxf(m, __shfl_xor(m, o, 16));
  float sum = 0.f;
#pragma unroll
  for (int i = 0; i < 4; i++) {
    v[i] = __expf(v[i] - m);
    sum += v[i];
  }
#pragma unroll
  for (int o = 1; o < 16; o <<= 1) sum += __shfl_xor(sum, o, 16);
  const float inv = 1.f / sum;

  u16x4 o4;
  o4.x = f2h(v[0] * inv); o4.y = f2h(v[1] * inv);
  o4.z = f2h(v[2] * inv); o4.w = f2h(v[3] * inv);
  *(u16x4*)(pP + (size_t)bh * 4096 + d * 64 + e4 * 4) = o4;
}

// ---------------- attention stage 3: O = P @ V over 256-token chunks ----------------
__global__ __launch_bounds__(256) void attn_pv(const unsigned short* __restrict__ pP,
                                               const unsigned short* __restrict__ vbuf,
                                               unsigned short* __restrict__ y) {
  __shared__ unsigned short tile[64 * 264];  // [d][256 tokens], stride 264 (33 KB)
  const int h = blockIdx.x, b = blockIdx.y, s = blockIdx.z;
  const int tid = threadIdx.x;
  const int wave = tid >> 6, lane = tid & 63;
  const int quad = lane >> 4, l15 = lane & 15;
  const int bh = b * 16 + h;

  const unsigned short* pp = pP + (size_t)bh * 4096 + (wave * 16 + l15) * 64 + quad * 8;
  f16x8 pa0 = *(const f16x8*)(pp);
  f16x8 pa1 = *(const f16x8*)(pp + 32);

  const unsigned short* vb =
      vbuf + (size_t)(b * 4096 + s * 256 + l15) * 1024 + h * 64 + quad * 8;

#pragma unroll 4
  for (int nt = 0; nt < 16; nt++) {
    const unsigned short* vp = vb + (size_t)nt * 16 * 1024;
    f16x8 v0 = *(const f16x8*)(vp);
    f16x8 v1 = *(const f16x8*)(vp + 32);
    f32x4 o = f32x4{0.f, 0.f, 0.f, 0.f};
    o = __builtin_amdgcn_mfma_f32_16x16x32_f16(pa0, v0, o, 0, 0, 0);
    o = __builtin_amdgcn_mfma_f32_16x16x32_f16(pa1, v1, o, 0, 0, 0);
    const int ncol = nt * 16 + l15;
#pragma unroll
    for (int rr = 0; rr < 4; rr++)
      tile[(wave * 16 + quad * 4 + rr) * 264 + ncol] = f2h(o[rr]);
  }
  __syncthreads();

  const int d = tid & 63, cc = tid >> 6;
  const int R = d * 64 + h * 4 + (s >> 2);
  unsigned short* dst =
      y + (size_t)b * 4194304 + (size_t)R * 1024 + (s & 3) * 256 + cc * 64;
  const unsigned short* srcp = &tile[d * 264 + cc * 64];
#pragma unroll
  for (int i = 0; i < 8; i++)
    *(u16x8*)(dst + i * 8) = *(const u16x8*)(srcp + i * 8);
}

extern "C" void kernel_launch(void* const* d_in, const int* in_sizes, int n_in, void* d_out,
                              int out_size, void* d_ws, size_t ws_size, hipStream_t stream) {
  (void)in_sizes; (void)n_in; (void)out_size; (void)ws_size;
  const float* x = (const float*)d_in[0];
  const float* Wq = (const float*)d_in[1];
  const float* Wk = (const float*)d_in[2];
  const float* Wv = (const float*)d_in[3];
  const float* Wp = (const float*)d_in[4];
  const float* bp = (const float*)d_in[5];

  char* ws = (char*)d_ws;
  unsigned short* xb = (unsigned short*)(ws);                        // 64 MB, x f16
  float* pbuf = (float*)(ws);                                        // 32 MB, aliases dead xb
  unsigned short* yb = xb;                                           // y aliases xb (after pbuf dead)
  unsigned short* qkt = (unsigned short*)(ws + (size_t)67108864);    // 128 MB, [2048][32768]
  unsigned short* pP = qkt;                                          // 0.5 MB, aliases dead qkt
  unsigned short* vbuf = (unsigned short*)(ws + (size_t)201326592);  // 64 MB, [32768][1024]
  unsigned short* wqkv = (unsigned short*)(ws + (size_t)268435456);  // 6 MB, [3072][1024]
  unsigned short* wp = (unsigned short*)(ws + (size_t)274726912);    // 2 MB

  cvt_f32_f16<<<32768, 256, 0, stream>>>(x, xb, 33554432);
  cvt4_f32_f16<<<dim3(1024, 4), 256, 0, stream>>>(Wq, Wk, Wv, Wp, wqkv, wqkv + 1048576,
                                                  wqkv + 2097152, wp);

  // fused Q,K,V projections: Q/K transposed [ch][token] -> qkt, V natural -> vbuf
  gemm256<EPI_QKV><<<1536, 512, 0, stream>>>(xb, wqkv, qkt, nullptr, 32768, 3072, 1024);

  // attention: partial logits -> reduce+softmax -> PV
  attn_logits<<<dim3(16, 8, 16), 256, 0, stream>>>(qkt, pbuf);
  attn_softmax<<<512, 256, 0, stream>>>(pbuf, pP);
  attn_pv<<<dim3(16, 8, 16), 256, 0, stream>>>(pP, vbuf, yb);

  // output projection + bias, fp32 out
  gemm256<EPI_F32_BIAS><<<512, 512, 0, stream>>>(yb, wp, (float*)d_out, bp, 32768, 1024, 1024);
}